// Round 1
// baseline (110584.900 us; speedup 1.0000x reference)
//
#include <hip/hip_runtime.h>
#include <math.h>

// Problem constants
constexpr int Bb  = 128;          // batch
constexpr int Hh  = 1024;         // hidden
constexpr int Tt  = 384;          // seq len (T2)
constexpr int BH  = Bb * Hh;
constexpr int NWG = 256;          // persistent workgroups (== CUs)
constexpr int BLK = 256;          // threads per WG
constexpr int KC  = 64;           // K chunk staged in LDS
constexpr int NKC = Hh / KC;      // 16
constexpr int JT  = 16;           // j-columns per WG  (64 WGs per layer)
constexpr int XP  = KC + 1;       // padded LDS row stride for X/H (bank spread)

__global__ void zero_init_kernel(float* __restrict__ p, int n) {
    int i = blockIdx.x * blockDim.x + threadIdx.x;
    if (i < n) p[i] = 0.0f;
}

__device__ inline void grid_barrier(unsigned* cnt, unsigned target) {
    __syncthreads();
    if (threadIdx.x == 0) {
        __threadfence();  // release h-state stores (device scope)
        __hip_atomic_fetch_add(cnt, 1u, __ATOMIC_RELEASE, __HIP_MEMORY_SCOPE_AGENT);
        while (__hip_atomic_load(cnt, __ATOMIC_ACQUIRE, __HIP_MEMORY_SCOPE_AGENT) < target) {
            __builtin_amdgcn_s_sleep(2);
        }
        __threadfence();  // acquire: invalidate stale cached h-state
    }
    __syncthreads();
}

// Persistent wavefront-pipelined 4-layer GRU.
// Layer k at macro-step s handles timestep tau = s-k. One device barrier per step.
// hbuf[(layer*2 + (tau&1))*BH + b*Hh + j] double-buffers each layer's hidden state.
__global__ __launch_bounds__(BLK, 1) void gru_persistent(
    const float* __restrict__ xin,   // rand_input (B,T,H)
    const float* __restrict__ h0,    // (2,B,H)
    const float* __restrict__ Wih0, const float* __restrict__ Whh0,
    const float* __restrict__ bih0, const float* __restrict__ bhh0,
    const float* __restrict__ Wih1, const float* __restrict__ Whh1,
    const float* __restrict__ bih1, const float* __restrict__ bhh1,
    unsigned* __restrict__ cnt,
    const float* __restrict__ zbuf,  // B*H zeros
    float* __restrict__ hbuf)        // 8 * B*H
{
    __shared__ float Xs[Bb * XP];        // 33,280 B
    __shared__ float Hs[Bb * XP];        // 33,280 B
    __shared__ float Wihs[48 * KC];      // 12,288 B
    __shared__ float Whhs[48 * KC];      // 12,288 B   -> 91,136 B total (1 WG/CU)

    const int bid   = blockIdx.x;
    const int layer = bid >> 6;          // 0..3
    const int jwg   = bid & 63;          // 0..63
    const int jbase = jwg * JT;
    const int tid   = threadIdx.x;
    const int rg    = tid & 63;          // rows rg, rg+64
    const int cg    = tid >> 6;          // j sub-block: cg*4 .. cg*4+3

    const float* Wih = (layer & 1) ? Wih1 : Wih0;
    const float* Whh = (layer & 1) ? Whh1 : Whh0;
    const float* bih = (layer & 1) ? bih1 : bih0;
    const float* bhh = (layer & 1) ? bhh1 : bhh0;

    unsigned target = NWG;
    for (int s = 0; s < Tt + 3; ++s, target += NWG) {
        const int tau = s - layer;
        if (tau >= 0 && tau < Tt) {
            // ---- sources / destination for this layer-step ----
            const float* xrow; size_t xstride;
            if (layer == 0) { xrow = xin + (size_t)tau * Hh; xstride = (size_t)Tt * Hh; }
            else            { xrow = hbuf + (size_t)(((layer - 1) * 2) + (tau & 1)) * BH; xstride = Hh; }
            const float* hrow;
            if (tau == 0)   hrow = (layer < 2) ? (h0 + (size_t)layer * BH) : zbuf;
            else            hrow = hbuf + (size_t)((layer * 2) + ((tau - 1) & 1)) * BH;
            float* hdst = hbuf + (size_t)((layer * 2) + (tau & 1)) * BH;

            float accx[2][3][4];
            float acch[2][3][4];
            #pragma unroll
            for (int a = 0; a < 2; ++a)
                #pragma unroll
                for (int g = 0; g < 3; ++g)
                    #pragma unroll
                    for (int jj = 0; jj < 4; ++jj) { accx[a][g][jj] = 0.f; acch[a][g][jj] = 0.f; }

            for (int kc = 0; kc < NKC; ++kc) {
                const int k0 = kc * KC;
                __syncthreads();   // LDS reuse guard
                // stage X and H chunks: 128 x 64 each, coalesced float4 loads
                for (int i = tid; i < (Bb * KC) / 4; i += BLK) {
                    int b = i >> 4;            // KC/4 == 16
                    int c = (i & 15) << 2;
                    float4 xv = *(const float4*)(xrow + (size_t)b * xstride + k0 + c);
                    float4 hv = *(const float4*)(hrow + (size_t)b * Hh + k0 + c);
                    float* xd = Xs + b * XP + c;
                    xd[0] = xv.x; xd[1] = xv.y; xd[2] = xv.z; xd[3] = xv.w;
                    float* hd = Hs + b * XP + c;
                    hd[0] = hv.x; hd[1] = hv.y; hd[2] = hv.z; hd[3] = hv.w;
                }
                // stage W chunks: 48 rows (3 gates x 16 j) x 64 k, both matrices
                for (int i = tid; i < (48 * KC) / 4; i += BLK) {   // 768
                    int wr = i >> 4;
                    int c  = (i & 15) << 2;
                    int g  = wr >> 4;
                    int jl = wr & 15;
                    size_t off = (size_t)(g * Hh + jbase + jl) * Hh + k0 + c;
                    *(float4*)(Wihs + wr * KC + c) = *(const float4*)(Wih + off);
                    *(float4*)(Whhs + wr * KC + c) = *(const float4*)(Whh + off);
                }
                __syncthreads();
                // compute: 48 FMAs/kk/thread, W reads are wave-uniform broadcasts
                #pragma unroll 4
                for (int kk = 0; kk < KC; ++kk) {
                    float xv0 = Xs[rg * XP + kk];
                    float xv1 = Xs[(rg + 64) * XP + kk];
                    float hv0 = Hs[rg * XP + kk];
                    float hv1 = Hs[(rg + 64) * XP + kk];
                    #pragma unroll
                    for (int g = 0; g < 3; ++g) {
                        #pragma unroll
                        for (int jj = 0; jj < 4; ++jj) {
                            const int w = g * 16 + cg * 4 + jj;
                            float wi = Wihs[w * KC + kk];
                            float wh = Whhs[w * KC + kk];
                            accx[0][g][jj] = fmaf(xv0, wi, accx[0][g][jj]);
                            accx[1][g][jj] = fmaf(xv1, wi, accx[1][g][jj]);
                            acch[0][g][jj] = fmaf(hv0, wh, acch[0][g][jj]);
                            acch[1][g][jj] = fmaf(hv1, wh, acch[1][g][jj]);
                        }
                    }
                }
            }
            // ---- gates + state update (each thread owns full r/z/n triples) ----
            #pragma unroll
            for (int rr = 0; rr < 2; ++rr) {
                const int b = rg + rr * 64;
                #pragma unroll
                for (int jj = 0; jj < 4; ++jj) {
                    const int j = jbase + cg * 4 + jj;
                    float xr = accx[rr][0][jj] + bih[j];
                    float hr = acch[rr][0][jj] + bhh[j];
                    float xz = accx[rr][1][jj] + bih[Hh + j];
                    float hz = acch[rr][1][jj] + bhh[Hh + j];
                    float xn = accx[rr][2][jj] + bih[2 * Hh + j];
                    float hn = acch[rr][2][jj] + bhh[2 * Hh + j];
                    float r  = 1.0f / (1.0f + expf(-(xr + hr)));
                    float z  = 1.0f / (1.0f + expf(-(xz + hz)));
                    float n  = tanhf(xn + r * hn);
                    float ho = hrow[(size_t)b * Hh + j];
                    hdst[(size_t)b * Hh + j] = (1.0f - z) * n + z * ho;
                }
            }
        }
        grid_barrier(cnt, target);
    }
}

__global__ void pred_kernel(const float* __restrict__ h3,
                            const float* __restrict__ linW,
                            const float* __restrict__ linb,
                            float* __restrict__ out) {
    const int b = blockIdx.x;
    const int l = threadIdx.x;   // 64 threads
    float s = 0.f;
    for (int u = l; u < Hh; u += 64) s += h3[(size_t)b * Hh + u] * linW[u];
    #pragma unroll
    for (int off = 32; off > 0; off >>= 1) s += __shfl_down(s, off);
    if (l == 0) out[b] = s + linb[0];
}

extern "C" void kernel_launch(void* const* d_in, const int* in_sizes, int n_in,
                              void* d_out, int out_size, void* d_ws, size_t ws_size,
                              hipStream_t stream) {
    const float* rand_in = (const float*)d_in[1];
    const float* h0      = (const float*)d_in[2];
    const float* Wih0    = (const float*)d_in[7];
    const float* Whh0    = (const float*)d_in[8];
    const float* bih0    = (const float*)d_in[9];
    const float* bhh0    = (const float*)d_in[10];
    const float* Wih1    = (const float*)d_in[11];
    const float* Whh1    = (const float*)d_in[12];
    const float* bih1    = (const float*)d_in[13];
    const float* bhh1    = (const float*)d_in[14];
    const float* linW    = (const float*)d_in[15];
    const float* linb    = (const float*)d_in[16];
    float* out = (float*)d_out;

    // ws layout (floats): [0..255] barrier counter+pad | [256..] zbuf (B*H) | hbuf (8*B*H)
    float*    wsf  = (float*)d_ws;
    unsigned* cnt  = (unsigned*)d_ws;
    float*    zbuf = wsf + 256;
    float*    hbuf = zbuf + BH;

    const int initN = 256 + BH;  // zero counter + zbuf
    zero_init_kernel<<<(initN + BLK - 1) / BLK, BLK, 0, stream>>>(wsf, initN);

    gru_persistent<<<NWG, BLK, 0, stream>>>(rand_in, h0,
                                            Wih0, Whh0, bih0, bhh0,
                                            Wih1, Whh1, bih1, bhh1,
                                            cnt, zbuf, hbuf);

    // h_last = layer 3, parity (383 & 1) = 1  ->  hbuf slot 7
    pred_kernel<<<Bb, 64, 0, stream>>>(hbuf + (size_t)7 * BH, linW, linb, out);
}

// Round 2
// 33376.480 us; speedup vs baseline: 3.3133x; 3.3133x over previous
//
#include <hip/hip_runtime.h>
#include <math.h>

// Problem constants
constexpr int Bb  = 128;          // batch
constexpr int Hh  = 1024;         // hidden
constexpr int Tt  = 384;          // seq len
constexpr int BH  = Bb * Hh;
constexpr int NWG = 256;          // persistent workgroups (4 layers x 64)
constexpr int BLK = 256;          // threads per WG (4 waves)
constexpr int KC  = 64;           // K chunk
constexpr int NCH = 32;           // 16 X-chunks + 16 H-chunks (K=2048 combined)
constexpr int PAD = 72;           // LDS row stride in bf16 (144B -> 2-way max)

typedef __attribute__((ext_vector_type(8))) __bf16          bf16x8;
typedef __attribute__((ext_vector_type(8))) unsigned short  ushort8;
typedef __attribute__((ext_vector_type(4))) float           f32x4;

__device__ inline unsigned short bf16_rn(float f) {
    unsigned u = __builtin_bit_cast(unsigned, f);
    u += 0x7FFFu + ((u >> 16) & 1u);          // round-to-nearest-even
    return (unsigned short)(u >> 16);
}
__device__ inline float bf16_to_f(unsigned short h) {
    unsigned u = ((unsigned)h) << 16;
    return __builtin_bit_cast(float, u);
}

__global__ void zero_init_kernel(float* __restrict__ p, int n) {
    int i = blockIdx.x * blockDim.x + threadIdx.x;
    if (i < n) p[i] = 0.0f;
}

__device__ inline void grid_barrier(unsigned* cnt, unsigned target) {
    __syncthreads();
    if (threadIdx.x == 0) {
        __threadfence();
        __hip_atomic_fetch_add(cnt, 1u, __ATOMIC_RELEASE, __HIP_MEMORY_SCOPE_AGENT);
        while (__hip_atomic_load(cnt, __ATOMIC_ACQUIRE, __HIP_MEMORY_SCOPE_AGENT) < target) {
            __builtin_amdgcn_s_sleep(2);
        }
        __threadfence();
    }
    __syncthreads();
}

// Persistent wavefront-pipelined 4-layer GRU, split-bf16 MFMA core.
__global__ __launch_bounds__(BLK, 1) void gru_persistent(
    const float* __restrict__ xin,   // rand_input (B,T,H)
    const float* __restrict__ h0,    // (2,B,H)
    const float* __restrict__ Wih0, const float* __restrict__ Whh0,
    const float* __restrict__ bih0, const float* __restrict__ bhh0,
    const float* __restrict__ Wih1, const float* __restrict__ Whh1,
    const float* __restrict__ bih1, const float* __restrict__ bhh1,
    unsigned* __restrict__ cnt,
    const float* __restrict__ zbuf,  // B*H zeros
    float* __restrict__ hbuf)        // 8 * B*H (4 layers x 2 parity)
{
    // [buf][hi/lo][row][col]
    __shared__ unsigned short As[2][2][Bb][PAD];   // 73,728 B
    __shared__ unsigned short Bs[2][2][48][PAD];   // 27,648 B  -> 101,376 B total

    const int bid   = blockIdx.x;
    const int layer = bid >> 6;          // 0..3
    const int jwg   = bid & 63;          // 0..63
    const int jbase = jwg * 16;
    const int tid   = threadIdx.x;
    const int lane  = tid & 63;
    const int wave  = tid >> 6;

    const float* Wih = (layer & 1) ? Wih1 : Wih0;
    const float* Whh = (layer & 1) ? Whh1 : Whh0;
    const float* bih = (layer & 1) ? bih1 : bih0;
    const float* bhh = (layer & 1) ? bhh1 : bhh0;

    // per-lane gate biases (constant across steps)
    const int jcol = jbase + (lane & 15);
    const float b_ir = bih[jcol],          b_hr = bhh[jcol];
    const float b_iz = bih[Hh + jcol],     b_hz = bhh[Hh + jcol];
    const float b_in = bih[2 * Hh + jcol], b_hn = bhh[2 * Hh + jcol];

    unsigned target = NWG;
    for (int s = 0; s < Tt + 3; ++s, target += NWG) {
        const int tau = s - layer;
        if (tau >= 0 && tau < Tt) {
            const float* xrow; size_t xstride;
            if (layer == 0) { xrow = xin + (size_t)tau * Hh; xstride = (size_t)Tt * Hh; }
            else            { xrow = hbuf + (size_t)(((layer - 1) * 2) + (tau & 1)) * BH; xstride = Hh; }
            const float* hrow;
            if (tau == 0)   hrow = (layer < 2) ? (h0 + (size_t)layer * BH) : zbuf;
            else            hrow = hbuf + (size_t)((layer * 2) + ((tau - 1) & 1)) * BH;
            float* hdst = hbuf + (size_t)((layer * 2) + (tau & 1)) * BH;

            const int c0 = (tid & 15) * 4;   // k offset within chunk (4 floats)
            const int r0 = tid >> 4;         // row group

            // ---- staging helpers ----
            auto issue = [&](int ch, float4 (&av)[8], float4 (&bv)[3]) {
                const float* asrc = (ch < 16) ? xrow : hrow;
                const size_t astr = (ch < 16) ? xstride : (size_t)Hh;
                const float* wsrc = (ch < 16) ? Wih : Whh;
                const int k0 = (ch & 15) * KC;
                #pragma unroll
                for (int i = 0; i < 8; ++i) {
                    int b = i * 16 + r0;
                    av[i] = *(const float4*)(asrc + (size_t)b * astr + k0 + c0);
                }
                #pragma unroll
                for (int i = 0; i < 3; ++i) {
                    int w = i * 16 + r0;                     // 0..47
                    size_t row = (size_t)(((w >> 4) << 10) + jbase + (w & 15));
                    bv[i] = *(const float4*)(wsrc + row * Hh + k0 + c0);
                }
            };
            auto store = [&](int nb, float4 (&av)[8], float4 (&bv)[3]) {
                #pragma unroll
                for (int i = 0; i < 8; ++i) {
                    const float* pv = (const float*)&av[i];
                    unsigned short h[4], l[4];
                    #pragma unroll
                    for (int m = 0; m < 4; ++m) {
                        float x = pv[m];
                        unsigned short hh = bf16_rn(x);
                        h[m] = hh;
                        l[m] = bf16_rn(x - bf16_to_f(hh));
                    }
                    int brow = i * 16 + r0;
                    uint2 hv, lv;
                    hv.x = h[0] | ((unsigned)h[1] << 16); hv.y = h[2] | ((unsigned)h[3] << 16);
                    lv.x = l[0] | ((unsigned)l[1] << 16); lv.y = l[2] | ((unsigned)l[3] << 16);
                    *(uint2*)&As[nb][0][brow][c0] = hv;
                    *(uint2*)&As[nb][1][brow][c0] = lv;
                }
                #pragma unroll
                for (int i = 0; i < 3; ++i) {
                    const float* pv = (const float*)&bv[i];
                    unsigned short h[4], l[4];
                    #pragma unroll
                    for (int m = 0; m < 4; ++m) {
                        float x = pv[m];
                        unsigned short hh = bf16_rn(x);
                        h[m] = hh;
                        l[m] = bf16_rn(x - bf16_to_f(hh));
                    }
                    int brow = i * 16 + r0;
                    uint2 hv, lv;
                    hv.x = h[0] | ((unsigned)h[1] << 16); hv.y = h[2] | ((unsigned)h[3] << 16);
                    lv.x = l[0] | ((unsigned)l[1] << 16); lv.y = l[2] | ((unsigned)l[3] << 16);
                    *(uint2*)&Bs[nb][0][brow][c0] = hv;
                    *(uint2*)&Bs[nb][1][brow][c0] = lv;
                }
            };
            auto compute = [&](int cur, f32x4 (&acc)[2][3]) {
                #pragma unroll
                for (int ks = 0; ks < 2; ++ks) {
                    const int koff = ks * 32 + (lane >> 4) * 8;
                    bf16x8 Ah[2], Al[2], Bh[3], Bl[3];
                    #pragma unroll
                    for (int rt = 0; rt < 2; ++rt) {
                        int row = wave * 32 + rt * 16 + (lane & 15);
                        Ah[rt] = __builtin_bit_cast(bf16x8, *(const ushort8*)&As[cur][0][row][koff]);
                        Al[rt] = __builtin_bit_cast(bf16x8, *(const ushort8*)&As[cur][1][row][koff]);
                    }
                    #pragma unroll
                    for (int g = 0; g < 3; ++g) {
                        int br = g * 16 + (lane & 15);
                        Bh[g] = __builtin_bit_cast(bf16x8, *(const ushort8*)&Bs[cur][0][br][koff]);
                        Bl[g] = __builtin_bit_cast(bf16x8, *(const ushort8*)&Bs[cur][1][br][koff]);
                    }
                    #pragma unroll
                    for (int rt = 0; rt < 2; ++rt)
                        #pragma unroll
                        for (int g = 0; g < 3; ++g) {
                            f32x4 c = acc[rt][g];
                            c = __builtin_amdgcn_mfma_f32_16x16x32_bf16(Ah[rt], Bh[g], c, 0, 0, 0);
                            c = __builtin_amdgcn_mfma_f32_16x16x32_bf16(Al[rt], Bh[g], c, 0, 0, 0);
                            c = __builtin_amdgcn_mfma_f32_16x16x32_bf16(Ah[rt], Bl[g], c, 0, 0, 0);
                            acc[rt][g] = c;
                        }
                }
            };

            // ---- K loop: X-part chunks 0..15 (accX), H-part chunks 16..31 (accH) ----
            f32x4 accX[2][3], accH[2][3];
            const f32x4 zv = {0.f, 0.f, 0.f, 0.f};
            #pragma unroll
            for (int rt = 0; rt < 2; ++rt)
                #pragma unroll
                for (int g = 0; g < 3; ++g) { accX[rt][g] = zv; accH[rt][g] = zv; }

            float4 av[8]; float4 bv[3];
            issue(0, av, bv);
            store(0, av, bv);
            __syncthreads();

            #pragma unroll
            for (int half = 0; half < 2; ++half) {
                auto& acc = half ? accH : accX;
                for (int kc = 0; kc < 16; ++kc) {
                    const int ch  = half * 16 + kc;
                    const int cur = ch & 1;
                    const bool hn = (ch + 1) < NCH;
                    if (hn) issue(ch + 1, av, bv);     // loads in flight under MFMA
                    compute(cur, acc);
                    if (hn) store(cur ^ 1, av, bv);    // waitcnt + convert + ds_write
                    __syncthreads();
                }
            }

            // ---- gates + state update (r,z,n of (b,j) all in this lane) ----
            #pragma unroll
            for (int rt = 0; rt < 2; ++rt) {
                #pragma unroll
                for (int q = 0; q < 4; ++q) {
                    const int b = wave * 32 + rt * 16 + (lane >> 4) * 4 + q;
                    float xr = accX[rt][0][q], hr = accH[rt][0][q];
                    float xz = accX[rt][1][q], hz = accH[rt][1][q];
                    float xn = accX[rt][2][q], hn_ = accH[rt][2][q];
                    float r  = 1.0f / (1.0f + expf(-(xr + b_ir + hr + b_hr)));
                    float z  = 1.0f / (1.0f + expf(-(xz + b_iz + hz + b_hz)));
                    float n  = tanhf(xn + b_in + r * (hn_ + b_hn));
                    float ho = hrow[(size_t)b * Hh + jcol];
                    hdst[(size_t)b * Hh + jcol] = (1.0f - z) * n + z * ho;
                }
            }
        }
        grid_barrier(cnt, target);
    }
}

__global__ void pred_kernel(const float* __restrict__ h3,
                            const float* __restrict__ linW,
                            const float* __restrict__ linb,
                            float* __restrict__ out) {
    const int b = blockIdx.x;
    const int l = threadIdx.x;   // 64 threads
    float s = 0.f;
    for (int u = l; u < Hh; u += 64) s += h3[(size_t)b * Hh + u] * linW[u];
    #pragma unroll
    for (int off = 32; off > 0; off >>= 1) s += __shfl_down(s, off);
    if (l == 0) out[b] = s + linb[0];
}

extern "C" void kernel_launch(void* const* d_in, const int* in_sizes, int n_in,
                              void* d_out, int out_size, void* d_ws, size_t ws_size,
                              hipStream_t stream) {
    const float* rand_in = (const float*)d_in[1];
    const float* h0      = (const float*)d_in[2];
    const float* Wih0    = (const float*)d_in[7];
    const float* Whh0    = (const float*)d_in[8];
    const float* bih0    = (const float*)d_in[9];
    const float* bhh0    = (const float*)d_in[10];
    const float* Wih1    = (const float*)d_in[11];
    const float* Whh1    = (const float*)d_in[12];
    const float* bih1    = (const float*)d_in[13];
    const float* bhh1    = (const float*)d_in[14];
    const float* linW    = (const float*)d_in[15];
    const float* linb    = (const float*)d_in[16];
    float* out = (float*)d_out;

    // ws layout (floats): [0..255] barrier counter+pad | zbuf (B*H) | hbuf (8*B*H)
    float*    wsf  = (float*)d_ws;
    unsigned* cnt  = (unsigned*)d_ws;
    float*    zbuf = wsf + 256;
    float*    hbuf = zbuf + BH;

    const int initN = 256 + BH;
    zero_init_kernel<<<(initN + BLK - 1) / BLK, BLK, 0, stream>>>(wsf, initN);

    gru_persistent<<<NWG, BLK, 0, stream>>>(rand_in, h0,
                                            Wih0, Whh0, bih0, bhh0,
                                            Wih1, Whh1, bih1, bhh1,
                                            cnt, zbuf, hbuf);

    // h_last = layer 3, parity (383 & 1) = 1 -> hbuf slot 7
    pred_kernel<<<Bb, 64, 0, stream>>>(hbuf + (size_t)7 * BH, linW, linb, out);
}

// Round 3
// 26407.327 us; speedup vs baseline: 4.1877x; 1.2639x over previous
//
#include <hip/hip_runtime.h>
#include <math.h>

typedef __attribute__((ext_vector_type(8))) __bf16          bf16x8;
typedef __attribute__((ext_vector_type(8))) unsigned short  ushort8;
typedef __attribute__((ext_vector_type(4))) float           f32x4;

constexpr int Bb = 128, Hh = 1024, Tt = 384, BH = Bb * Hh;
constexpr int NWG = 256, BLK = 256;

// A-tile image: [plane2][kc16][row128][col64] ushort, swizzled: byte = row*128 + ((col*2)^((row&7)<<4))
constexpr size_t SLOT_B  = 2ull * 16 * 128 * 64 * 2;    // 524,288 B
constexpr size_t OFF_H   = 1024;
constexpr size_t OFF_W   = OFF_H + 8 * SLOT_B;          // hsplit: 8 slots
constexpr size_t WBLK_B  = 2ull * 48 * 64 * 2;          // 12,288 B per (m,jwg,kc) block
constexpr size_t OFF_X   = OFF_W + 4096ull * WBLK_B;    // wbuf: 4 mats x 64 jwg x 16 kc
constexpr size_t WS_FULL = OFF_X + 384ull * SLOT_B;     // + xsplit(384 tiles) ~= 244 MB

__device__ __forceinline__ float b2f(unsigned short h) {
    unsigned u = ((unsigned)h) << 16;
    return __builtin_bit_cast(float, u);
}
__device__ __forceinline__ void split_bf16(float x, unsigned short& hi, unsigned short& lo) {
    unsigned u  = __builtin_bit_cast(unsigned, x);
    unsigned uh = u & 0xFFFF0000u;
    hi = (unsigned short)(uh >> 16);
    float rem = x - __builtin_bit_cast(float, uh);     // exact
    unsigned ur = __builtin_bit_cast(unsigned, rem);
    ur += 0x7FFFu + ((ur >> 16) & 1u);                 // RNE
    lo = (unsigned short)(ur >> 16);
}
__device__ __forceinline__ void split8(const float* src, ushort8& h8, ushort8& l8) {
    const float4* p4 = (const float4*)src;
    float4 a = p4[0], b = p4[1];
    float v[8] = {a.x, a.y, a.z, a.w, b.x, b.y, b.z, b.w};
    #pragma unroll
    for (int m = 0; m < 8; ++m) { unsigned short h, l; split_bf16(v[m], h, l); h8[m] = h; l8[m] = l; }
}
__device__ __forceinline__ void async16(const void* g, void* l) {
    __builtin_amdgcn_global_load_lds(
        (const __attribute__((address_space(1))) unsigned int*)g,
        (__attribute__((address_space(3))) unsigned int*)l, 16, 0, 0);
}

// ---------------- prologue kernels ----------------

// weights -> wbuf[m4][jwg64][kc16]{hi[48][64], lo[48][64]} swizzled. m: 0=Wih0 1=Whh0 2=Wih1 3=Whh1
__global__ void wsplit_kernel(const float* __restrict__ W0i, const float* __restrict__ W0h,
                              const float* __restrict__ W1i, const float* __restrict__ W1h,
                              unsigned short* __restrict__ wbuf) {
    int t = blockIdx.x * 256 + threadIdx.x;
    if (t >= 4 * 64 * 16 * 48 * 8) return;
    int g8 = t & 7;
    int r  = (t >> 3) % 48;
    int rest = (t >> 3) / 48;           // ((m*64+jwg)*16+kc)
    const float* W = (rest >> 10) == 0 ? W0i : (rest >> 10) == 1 ? W0h : (rest >> 10) == 2 ? W1i : W1h;
    int kc = rest & 15, jq = (rest >> 4) & 63;
    int gate = r >> 4, jl = r & 15;
    const float* src = W + (size_t)(gate * 1024 + jq * 16 + jl) * 1024 + kc * 64 + g8 * 8;
    ushort8 h8, l8; split8(src, h8, l8);
    unsigned short* blk = wbuf + (size_t)rest * 6144;
    int boff = r * 128 + ((g8 * 16) ^ ((r & 7) << 4));   // bytes within plane
    *(ushort8*)(blk + (boff >> 1))        = h8;
    *(ushort8*)(blk + 3072 + (boff >> 1)) = l8;
}

// rand_input (B,T,H) -> xsplit[tau][plane][kc][128][64] swizzled (row = batch b)
__global__ void xsplit_kernel(const float* __restrict__ xin, unsigned short* __restrict__ xb) {
    int t = blockIdx.x * 256 + threadIdx.x;
    if (t >= 384 * 128 * 128) return;
    int g = t & 127, b = (t >> 7) & 127, tau = t >> 14;
    const float* src = xin + ((size_t)b * 384 + tau) * 1024 + g * 8;
    ushort8 h8, l8; split8(src, h8, l8);
    int kc = g >> 3;
    int boff = b * 128 + (((g & 7) * 16) ^ ((b & 7) << 4));
    unsigned short* dst = xb + (size_t)tau * 262144 + (size_t)kc * 8192 + (boff >> 1);
    dst[0] = 0; // placate nothing; overwritten below (kept simple)
    *(ushort8*)dst            = h8;
    *(ushort8*)(dst + 131072) = l8;
}

// h0 -> slots 1,3 ; zeros -> slots 5,7 ; zero barrier counter
__global__ void hinit_kernel(const float* __restrict__ h0, char* __restrict__ hs, unsigned* __restrict__ cnt) {
    int t = blockIdx.x * 256 + threadIdx.x;
    if (t == 0) *cnt = 0;
    if (t >= 4 * 128 * 128) return;
    int g = t & 127, b = (t >> 7) & 127, si = t >> 14;   // si 0..3 -> slot 1,3,5,7
    ushort8 h8, l8;
    if (si < 2) {
        split8(h0 + (size_t)si * BH + (size_t)b * 1024 + g * 8, h8, l8);
    } else {
        #pragma unroll
        for (int m = 0; m < 8; ++m) { h8[m] = 0; l8[m] = 0; }
    }
    int kc = g >> 3;
    int boff = b * 128 + (((g & 7) * 16) ^ ((b & 7) << 4));
    char* dst = hs + (size_t)(si * 2 + 1) * SLOT_B + (size_t)kc * 16384 + boff;
    *(ushort8*)dst            = h8;
    *(ushort8*)(dst + 262144) = l8;
}

// ---------------- main persistent kernel ----------------

__device__ __forceinline__ void grid_barrier(unsigned* cnt, unsigned target) {
    __syncthreads();
    if (threadIdx.x == 0) {
        __threadfence();
        __hip_atomic_fetch_add(cnt, 1u, __ATOMIC_RELEASE, __HIP_MEMORY_SCOPE_AGENT);
        while (__hip_atomic_load(cnt, __ATOMIC_ACQUIRE, __HIP_MEMORY_SCOPE_AGENT) < target) {
            __builtin_amdgcn_s_sleep(2);
        }
        __threadfence();
    }
    __syncthreads();
}

template<bool XS>
__global__ __launch_bounds__(BLK, 1) void gru_persistent(
    const float* __restrict__ xin,
    const float* __restrict__ bih0, const float* __restrict__ bhh0,
    const float* __restrict__ bih1, const float* __restrict__ bhh1,
    unsigned* __restrict__ cnt, char* __restrict__ ws)
{
    __shared__ unsigned short As[2][2][128 * 64];   // 64 KiB  (buf, plane)
    __shared__ unsigned short Bsm[2][2][48 * 64];   // 24 KiB

    char* hs = ws + OFF_H;
    char* wb = ws + OFF_W;
    char* xs = ws + OFF_X;

    const int bid = blockIdx.x, layer = bid >> 6, jwg = bid & 63, jbase = jwg * 16;
    const int tid = threadIdx.x, lane = tid & 63, wave = tid >> 6;

    const float* bih = (layer & 1) ? bih1 : bih0;
    const float* bhh = (layer & 1) ? bhh1 : bhh0;
    const int jcol = jbase + (lane & 15);
    const int kcj = jcol >> 6, colj = jcol & 63;
    const float b_ir = bih[jcol],          b_hr = bhh[jcol];
    const float b_iz = bih[Hh + jcol],     b_hz = bhh[Hh + jcol];
    const float b_in = bih[2 * Hh + jcol], b_hn = bhh[2 * Hh + jcol];

    auto hoff = [&](int b, int plane) -> size_t {
        return (size_t)plane * 262144 + (size_t)kcj * 16384 + (size_t)(b * 128 + (((colj * 2) ^ ((b & 7) << 4))));
    };

    float hreg[8];   // persistent h_old for this lane's (8 b's, jcol)

    unsigned target = NWG;
    for (int s = 0; s < Tt + 3; ++s, target += NWG) {
        const int tau = s - layer;
        if (tau >= 0 && tau < Tt) {
            const char* Axb = (layer == 0) ? (xs + (size_t)tau * SLOT_B)
                                           : (hs + (size_t)(((layer - 1) * 2) + (tau & 1)) * SLOT_B);
            const char* Ahb = hs + (size_t)((layer * 2) + ((tau - 1) & 1)) * SLOT_B;
            char*       Hd  = hs + (size_t)((layer * 2) + (tau & 1)) * SLOT_B;

            if (tau == 0) {
                #pragma unroll
                for (int rt = 0; rt < 2; ++rt)
                    #pragma unroll
                    for (int q = 0; q < 4; ++q) {
                        int b = wave * 32 + rt * 16 + (lane >> 4) * 4 + q;
                        hreg[rt * 4 + q] = b2f(*(const unsigned short*)(Ahb + hoff(b, 0)))
                                         + b2f(*(const unsigned short*)(Ahb + hoff(b, 1)));
                    }
            }

            auto stage = [&](int ch, int nb) {
                const int kc = ch & 15;
                const bool isX = ch < 16;
                const char* Ab = isX ? Axb : Ahb;
                const int m = (layer & 1) * 2 + (isX ? 0 : 1);
                const char* Wb = wb + (size_t)((m * 64 + jwg) * 16 + kc) * WBLK_B;
                if (XS || layer != 0 || !isX) {
                    #pragma unroll
                    for (int i = 0; i < 11; ++i) {
                        const int seg = wave + i * 4;
                        if (i < 8) {   // A segs 0..31
                            int p = seg >> 4, sub = seg & 15;
                            async16(Ab + (size_t)p * 262144 + (size_t)kc * 16384 + sub * 1024 + lane * 16,
                                    (char*)&As[nb][p][0] + sub * 1024);
                        } else {       // B segs 32..43
                            int s2 = seg - 32;
                            int p = (s2 >= 6) ? 1 : 0, sub = s2 - p * 6;
                            async16(Wb + (size_t)p * 6144 + sub * 1024 + lane * 16,
                                    (char*)&Bsm[nb][p][0] + sub * 1024);
                        }
                    }
                } else {
                    // layer-0 X fallback: manual convert+swizzled ds_write; B via async
                    #pragma unroll
                    for (int u = 0; u < 4; ++u) {
                        int unit = tid + u * 256;           // 0..1023
                        int r = unit >> 3, g8 = unit & 7;
                        ushort8 h8, l8;
                        split8(xin + ((size_t)r * 384 + tau) * 1024 + kc * 64 + g8 * 8, h8, l8);
                        int boff = r * 128 + ((g8 * 16) ^ ((r & 7) << 4));
                        *(ushort8*)((char*)&As[nb][0][0] + boff) = h8;
                        *(ushort8*)((char*)&As[nb][1][0] + boff) = l8;
                    }
                    #pragma unroll
                    for (int i = 0; i < 3; ++i) {
                        int s2 = wave + i * 4;             // 0..11
                        int p = (s2 >= 6) ? 1 : 0, sub = s2 - p * 6;
                        async16(Wb + (size_t)p * 6144 + sub * 1024 + lane * 16,
                                (char*)&Bsm[nb][p][0] + sub * 1024);
                    }
                }
            };

            auto compute = [&](int cur, f32x4 (&acc)[2][3]) {
                #pragma unroll
                for (int ks = 0; ks < 2; ++ks) {
                    const int kb = ks * 64 + (lane >> 4) * 16;   // byte offset in k
                    bf16x8 Ah[2], Al[2], Bh[3], Bl[3];
                    #pragma unroll
                    for (int rt = 0; rt < 2; ++rt) {
                        int row = wave * 32 + rt * 16 + (lane & 15);
                        int off = row * 128 + (kb ^ ((row & 7) << 4));
                        Ah[rt] = __builtin_bit_cast(bf16x8, *(const ushort8*)((const char*)&As[cur][0][0] + off));
                        Al[rt] = __builtin_bit_cast(bf16x8, *(const ushort8*)((const char*)&As[cur][1][0] + off));
                    }
                    #pragma unroll
                    for (int g = 0; g < 3; ++g) {
                        int row = g * 16 + (lane & 15);
                        int off = row * 128 + (kb ^ ((row & 7) << 4));
                        Bh[g] = __builtin_bit_cast(bf16x8, *(const ushort8*)((const char*)&Bsm[cur][0][0] + off));
                        Bl[g] = __builtin_bit_cast(bf16x8, *(const ushort8*)((const char*)&Bsm[cur][1][0] + off));
                    }
                    #pragma unroll
                    for (int rt = 0; rt < 2; ++rt)
                        #pragma unroll
                        for (int g = 0; g < 3; ++g) {
                            f32x4 c = acc[rt][g];
                            c = __builtin_amdgcn_mfma_f32_16x16x32_bf16(Ah[rt], Bh[g], c, 0, 0, 0);
                            c = __builtin_amdgcn_mfma_f32_16x16x32_bf16(Al[rt], Bh[g], c, 0, 0, 0);
                            c = __builtin_amdgcn_mfma_f32_16x16x32_bf16(Ah[rt], Bl[g], c, 0, 0, 0);
                            acc[rt][g] = c;
                        }
                }
            };

            f32x4 accX[2][3], accH[2][3];
            const f32x4 zv = {0.f, 0.f, 0.f, 0.f};
            #pragma unroll
            for (int rt = 0; rt < 2; ++rt)
                #pragma unroll
                for (int g = 0; g < 3; ++g) { accX[rt][g] = zv; accH[rt][g] = zv; }

            stage(0, 0);
            __syncthreads();
            for (int ch = 0; ch < 32; ++ch) {
                const int cur = ch & 1;
                if (ch + 1 < 32) stage(ch + 1, cur ^ 1);
                if (ch < 16) compute(cur, accX); else compute(cur, accH);
                __syncthreads();
            }

            // epilogue: gates + state update; h_old from registers
            #pragma unroll
            for (int rt = 0; rt < 2; ++rt)
                #pragma unroll
                for (int q = 0; q < 4; ++q) {
                    const int b = wave * 32 + rt * 16 + (lane >> 4) * 4 + q;
                    float xr = accX[rt][0][q], hr = accH[rt][0][q];
                    float xz = accX[rt][1][q], hz = accH[rt][1][q];
                    float xn = accX[rt][2][q], hn_ = accH[rt][2][q];
                    float r  = 1.0f / (1.0f + expf(-(xr + b_ir + hr + b_hr)));
                    float z  = 1.0f / (1.0f + expf(-(xz + b_iz + hz + b_hz)));
                    float n  = tanhf(xn + b_in + r * (hn_ + b_hn));
                    float h  = (1.0f - z) * n + z * hreg[rt * 4 + q];
                    hreg[rt * 4 + q] = h;
                    unsigned short hi, lo; split_bf16(h, hi, lo);
                    *(unsigned short*)(Hd + hoff(b, 0)) = hi;
                    *(unsigned short*)(Hd + hoff(b, 1)) = lo;
                }
        }
        grid_barrier(cnt, target);
    }
}

__global__ void pred_kernel(const char* __restrict__ hs,
                            const float* __restrict__ linW,
                            const float* __restrict__ linb,
                            float* __restrict__ out) {
    const int b = blockIdx.x, l = threadIdx.x;   // 64 threads
    const char* slot = hs + 7 * SLOT_B;
    float s = 0.f;
    for (int u = l; u < Hh; u += 64) {
        int kc = u >> 6, col = u & 63;
        size_t o = (size_t)kc * 16384 + (size_t)(b * 128 + (((col * 2) ^ ((b & 7) << 4))));
        float hv = b2f(*(const unsigned short*)(slot + o)) + b2f(*(const unsigned short*)(slot + 262144 + o));
        s += hv * linW[u];
    }
    #pragma unroll
    for (int off = 32; off > 0; off >>= 1) s += __shfl_down(s, off);
    if (l == 0) out[b] = s + linb[0];
}

extern "C" void kernel_launch(void* const* d_in, const int* in_sizes, int n_in,
                              void* d_out, int out_size, void* d_ws, size_t ws_size,
                              hipStream_t stream) {
    const float* rand_in = (const float*)d_in[1];
    const float* h0      = (const float*)d_in[2];
    const float* Wih0    = (const float*)d_in[7];
    const float* Whh0    = (const float*)d_in[8];
    const float* bih0    = (const float*)d_in[9];
    const float* bhh0    = (const float*)d_in[10];
    const float* Wih1    = (const float*)d_in[11];
    const float* Whh1    = (const float*)d_in[12];
    const float* bih1    = (const float*)d_in[13];
    const float* bhh1    = (const float*)d_in[14];
    const float* linW    = (const float*)d_in[15];
    const float* linb    = (const float*)d_in[16];
    float* out = (float*)d_out;

    char*     ws   = (char*)d_ws;
    unsigned* cnt  = (unsigned*)d_ws;
    char*     hsl  = ws + OFF_H;

    const bool xs = (ws_size >= WS_FULL);

    wsplit_kernel<<<6144, 256, 0, stream>>>(Wih0, Whh0, Wih1, Whh1, (unsigned short*)(ws + OFF_W));
    hinit_kernel<<<256, 256, 0, stream>>>(h0, hsl, cnt);
    if (xs) {
        xsplit_kernel<<<24576, 256, 0, stream>>>(rand_in, (unsigned short*)(ws + OFF_X));
        gru_persistent<true><<<NWG, BLK, 0, stream>>>(rand_in, bih0, bhh0, bih1, bhh1, cnt, ws);
    } else {
        gru_persistent<false><<<NWG, BLK, 0, stream>>>(rand_in, bih0, bhh0, bih1, bhh1, cnt, ws);
    }
    pred_kernel<<<Bb, 64, 0, stream>>>(hsl, linW, linb, out);
}

// Round 4
// 21243.759 us; speedup vs baseline: 5.2055x; 1.2431x over previous
//
#include <hip/hip_runtime.h>
#include <math.h>

typedef __attribute__((ext_vector_type(8))) __bf16          bf16x8;
typedef __attribute__((ext_vector_type(8))) unsigned short  ushort8;
typedef __attribute__((ext_vector_type(4))) float           f32x4;

constexpr int Bb = 128, Hh = 1024, Tt = 384, BH = Bb * Hh;
constexpr int NWG = 256, BLK = 256;

// h/x tile image: [plane2][kc16][row128][col64] ushort, swizzled:
//   byte = kc*16384 + row*128 + ((col*2) ^ ((row&7)<<4)); plane stride 262144 B
constexpr size_t SLOT_B  = 524288;                       // one (B=128,K=1024) split tile
constexpr size_t OFF_H   = 1024;
constexpr size_t OFF_W   = OFF_H + 8 * SLOT_B;           // h slots: 4 layers x 2 parity
constexpr size_t WBLK_B  = 12288;                        // per (m,jwg,kc): hi[48][64], lo[48][64]
constexpr size_t OFF_X   = OFF_W + 4096ull * WBLK_B;     // wbuf: 4 mats x 64 jwg x 16 kc
constexpr size_t WS_FULL = OFF_X + 384ull * SLOT_B;      // + xsplit (384 tiles)

__device__ __forceinline__ float b2f(unsigned short h) {
    unsigned u = ((unsigned)h) << 16;
    return __builtin_bit_cast(float, u);
}
__device__ __forceinline__ void split_bf16(float x, unsigned short& hi, unsigned short& lo) {
    unsigned u  = __builtin_bit_cast(unsigned, x);
    unsigned uh = u & 0xFFFF0000u;
    hi = (unsigned short)(uh >> 16);
    float rem = x - __builtin_bit_cast(float, uh);     // exact
    unsigned ur = __builtin_bit_cast(unsigned, rem);
    ur += 0x7FFFu + ((ur >> 16) & 1u);                 // RNE
    lo = (unsigned short)(ur >> 16);
}
__device__ __forceinline__ void split8(const float* src, ushort8& h8, ushort8& l8) {
    const float4* p4 = (const float4*)src;
    float4 a = p4[0], b = p4[1];
    float v[8] = {a.x, a.y, a.z, a.w, b.x, b.y, b.z, b.w};
    #pragma unroll
    for (int m = 0; m < 8; ++m) { unsigned short h, l; split_bf16(v[m], h, l); h8[m] = h; l8[m] = l; }
}
__device__ __forceinline__ void async16(const void* g, void* l) {
    __builtin_amdgcn_global_load_lds(
        (const __attribute__((address_space(1))) unsigned int*)g,
        (__attribute__((address_space(3))) unsigned int*)l, 16, 0, 0);
}
// coherent (bypass L1+L2, read from coherent point): CPol SC0|SC1 = 1|16
__device__ __forceinline__ void async16_coh(const void* g, void* l) {
    __builtin_amdgcn_global_load_lds(
        (const __attribute__((address_space(1))) unsigned int*)g,
        (__attribute__((address_space(3))) unsigned int*)l, 16, 0, 17);
}

// ---------------- prologue kernels ----------------

// weights -> wbuf[m4][jwg64][kc16]{hi[48][64], lo[48][64]} swizzled. m: 0=Wih0 1=Whh0 2=Wih1 3=Whh1
__global__ void wsplit_kernel(const float* __restrict__ W0i, const float* __restrict__ W0h,
                              const float* __restrict__ W1i, const float* __restrict__ W1h,
                              unsigned short* __restrict__ wbuf) {
    int t = blockIdx.x * 256 + threadIdx.x;
    if (t >= 4 * 64 * 16 * 48 * 8) return;
    int g8 = t & 7;
    int r  = (t >> 3) % 48;
    int rest = (t >> 3) / 48;           // ((m*64+jwg)*16+kc)
    const float* W = (rest >> 10) == 0 ? W0i : (rest >> 10) == 1 ? W0h : (rest >> 10) == 2 ? W1i : W1h;
    int kc = rest & 15, jq = (rest >> 4) & 63;
    int gate = r >> 4, jl = r & 15;
    const float* src = W + (size_t)(gate * 1024 + jq * 16 + jl) * 1024 + kc * 64 + g8 * 8;
    ushort8 h8, l8; split8(src, h8, l8);
    unsigned short* blk = wbuf + (size_t)rest * 6144;
    int boff = r * 128 + ((g8 * 16) ^ ((r & 7) << 4));   // bytes within plane
    *(ushort8*)((char*)blk + boff)        = h8;
    *(ushort8*)((char*)blk + 6144 + boff) = l8;
}

// rand_input (B,T,H) -> xsplit[tau][plane][kc][128][64] swizzled (row = batch b)
__global__ void xsplit_kernel(const float* __restrict__ xin, char* __restrict__ xb) {
    int t = blockIdx.x * 256 + threadIdx.x;
    if (t >= 384 * 16 * 128 * 8) return;
    int c8 = t & 7, b = (t >> 3) & 127, kc = (t >> 10) & 15, tau = t >> 14;
    const float* src = xin + ((size_t)b * 384 + tau) * 1024 + kc * 64 + c8 * 8;
    ushort8 h8, l8; split8(src, h8, l8);
    int boff = b * 128 + ((c8 * 16) ^ ((b & 7) << 4));
    char* dst = xb + (size_t)tau * SLOT_B + (size_t)kc * 16384 + boff;
    *(ushort8*)dst            = h8;
    *(ushort8*)(dst + 262144) = l8;
}

// h0 -> slots 1,3 ; zeros -> slots 5,7 ; zero barrier counter
__global__ void hinit_kernel(const float* __restrict__ h0, char* __restrict__ hs, unsigned* __restrict__ cnt) {
    int t = blockIdx.x * 256 + threadIdx.x;
    if (t == 0) *cnt = 0;
    if (t >= 4 * 128 * 128) return;
    int g = t & 127, b = (t >> 7) & 127, si = t >> 14;   // si 0..3 -> slot 1,3,5,7
    ushort8 h8, l8;
    if (si < 2) {
        split8(h0 + (size_t)si * BH + (size_t)b * 1024 + g * 8, h8, l8);
    } else {
        #pragma unroll
        for (int m = 0; m < 8; ++m) { h8[m] = 0; l8[m] = 0; }
    }
    int kc = g >> 3;
    int boff = b * 128 + (((g & 7) * 16) ^ ((b & 7) << 4));
    char* dst = hs + (size_t)(si * 2 + 1) * SLOT_B + (size_t)kc * 16384 + boff;
    *(ushort8*)dst            = h8;
    *(ushort8*)(dst + 262144) = l8;
}

// ---------------- main persistent kernel ----------------

__device__ __forceinline__ void grid_barrier(unsigned* cnt, unsigned target) {
    __syncthreads();   // all waves drain vmcnt(0): h atomic stores complete (coherent point)
    if (threadIdx.x == 0) {
        __hip_atomic_fetch_add(cnt, 1u, __ATOMIC_RELEASE, __HIP_MEMORY_SCOPE_AGENT);
        while (__hip_atomic_load(cnt, __ATOMIC_RELAXED, __HIP_MEMORY_SCOPE_AGENT) < target)
            __builtin_amdgcn_s_sleep(1);
    }
    __syncthreads();
}

template<bool XS>
__global__ __launch_bounds__(BLK, 1) void gru_persistent(
    const float* __restrict__ xin,
    const float* __restrict__ bih0, const float* __restrict__ bhh0,
    const float* __restrict__ bih1, const float* __restrict__ bhh1,
    unsigned* __restrict__ cnt, char* __restrict__ ws)
{
    __shared__ char AsB[3][2][16384];   // 96 KiB: 3 bufs x {hi,lo} x [128][64] bf16 (swizzled)
    __shared__ char BsB[3][2][6144];    // 36 KiB: 3 bufs x {hi,lo} x [48][64]  bf16 (swizzled)

    char*       hs = ws + OFF_H;
    const char* wb = ws + OFF_W;
    const char* xs = ws + OFF_X;

    const int bid = blockIdx.x, layer = bid >> 6, jwg = bid & 63, jbase = jwg * 16;
    const int tid = threadIdx.x, lane = tid & 63, wave = tid >> 6;

    const float* bih = (layer & 1) ? bih1 : bih0;
    const float* bhh = (layer & 1) ? bhh1 : bhh0;
    const int jcol = jbase + (lane & 15);
    const int kcj = jcol >> 6, colj = jcol & 63;
    const float b_ir = bih[jcol],          b_hr = bhh[jcol];
    const float b_iz = bih[Hh + jcol],     b_hz = bhh[Hh + jcol];
    const float b_in = bih[2 * Hh + jcol], b_hn = bhh[2 * Hh + jcol];

    auto hoff = [&](int b, int plane) -> size_t {
        return (size_t)plane * 262144 + (size_t)kcj * 16384
             + (size_t)(b * 128 + (((colj * 2) ^ ((b & 7) << 4))));
    };

    float hreg[8];   // persistent h_old for this lane's (8 b's, jcol)

    unsigned target = NWG;
    for (int s = 0; s < Tt + 3; ++s, target += NWG) {
        const int tau = s - layer;
        if (tau >= 0 && tau < Tt) {
            const char* Axb = (layer == 0) ? (xs + (size_t)tau * SLOT_B)
                                           : (hs + (size_t)(((layer - 1) * 2) + (tau & 1)) * SLOT_B);
            const char* Ahb = hs + (size_t)((layer * 2) + ((tau - 1) & 1)) * SLOT_B;
            char*       Hd  = hs + (size_t)((layer * 2) + (tau & 1)) * SLOT_B;

            if (tau == 0) {
                if (layer < 2) {
                    #pragma unroll
                    for (int rt = 0; rt < 2; ++rt)
                        #pragma unroll
                        for (int q = 0; q < 4; ++q) {
                            int b = wave * 32 + rt * 16 + (lane >> 4) * 4 + q;
                            unsigned short hi = __hip_atomic_load(
                                (const unsigned short*)(Ahb + hoff(b, 0)),
                                __ATOMIC_RELAXED, __HIP_MEMORY_SCOPE_AGENT);
                            unsigned short lo = __hip_atomic_load(
                                (const unsigned short*)(Ahb + hoff(b, 1)),
                                __ATOMIC_RELAXED, __HIP_MEMORY_SCOPE_AGENT);
                            hreg[rt * 4 + q] = b2f(hi) + b2f(lo);
                        }
                    asm volatile("s_waitcnt vmcnt(0)" ::: "memory");  // keep DMA vmcnt bookkeeping clean
                } else {
                    #pragma unroll
                    for (int i = 0; i < 8; ++i) hreg[i] = 0.f;
                }
            }

            // ---- stage one K=64 chunk via global_load_lds (44 segs = 11/wave) ----
            auto stageDMA = [&](int ch, int nb) {
                const int kc = ch & 15;
                const bool isX = ch < 16;
                const char* Ab = isX ? Axb : Ahb;
                const bool cohA = !(isX && layer == 0);   // h tiles need coherent reads
                const int m = (layer & 1) * 2 + (isX ? 0 : 1);
                const char* Wb = wb + (size_t)((m * 64 + jwg) * 16 + kc) * WBLK_B;
                #pragma unroll
                for (int i = 0; i < 11; ++i) {
                    int seg = wave + i * 4;
                    if (seg < 32) {        // A: 2 planes x 16 segs of 1 KiB
                        int p = seg >> 4, sub = seg & 15;
                        const char* g = Ab + (size_t)p * 262144 + (size_t)kc * 16384
                                      + sub * 1024 + lane * 16;
                        char* l = &AsB[nb][p][sub * 1024];
                        if (cohA) async16_coh(g, l); else async16(g, l);
                    } else {               // B: 2 planes x 6 segs of 1 KiB
                        int s2 = seg - 32;
                        int p = (s2 >= 6) ? 1 : 0, sub = s2 - p * 6;
                        async16(Wb + (size_t)p * 6144 + sub * 1024 + lane * 16,
                                &BsB[nb][p][sub * 1024]);
                    }
                }
            };

            // fallback staging (no xsplit image): layer-0 X = on-the-fly split + ds_write
            auto stageF = [&](int ch, int nb) {
                if (!XS && layer == 0 && ch < 16) {
                    const int kc = ch;
                    #pragma unroll
                    for (int u = 0; u < 4; ++u) {
                        int unit = tid + u * 256;           // 0..1023
                        int r = unit >> 3, g8 = unit & 7;
                        ushort8 h8, l8;
                        split8(xin + ((size_t)r * 384 + tau) * 1024 + kc * 64 + g8 * 8, h8, l8);
                        int boff = r * 128 + ((g8 * 16) ^ ((r & 7) << 4));
                        *(ushort8*)(&AsB[nb][0][0] + boff) = h8;
                        *(ushort8*)(&AsB[nb][1][0] + boff) = l8;
                    }
                    const int m = (layer & 1) * 2;
                    const char* Wb = wb + (size_t)((m * 64 + jwg) * 16 + kc) * WBLK_B;
                    #pragma unroll
                    for (int i = 0; i < 3; ++i) {
                        int s2 = wave + i * 4;
                        int p = (s2 >= 6) ? 1 : 0, sub = s2 - p * 6;
                        async16(Wb + (size_t)p * 6144 + sub * 1024 + lane * 16,
                                &BsB[nb][p][sub * 1024]);
                    }
                } else {
                    stageDMA(ch, nb);
                }
            };

            auto compute = [&](int cur, f32x4 (&acc)[2][3]) {
                #pragma unroll
                for (int ks = 0; ks < 2; ++ks) {
                    const int kb = ks * 64 + (lane >> 4) * 16;   // byte offset in k
                    bf16x8 Ah[2], Al[2], Bh[3], Bl[3];
                    #pragma unroll
                    for (int rt = 0; rt < 2; ++rt) {
                        int row = wave * 32 + rt * 16 + (lane & 15);
                        int off = row * 128 + (kb ^ ((row & 7) << 4));
                        Ah[rt] = __builtin_bit_cast(bf16x8, *(const ushort8*)(&AsB[cur][0][0] + off));
                        Al[rt] = __builtin_bit_cast(bf16x8, *(const ushort8*)(&AsB[cur][1][0] + off));
                    }
                    #pragma unroll
                    for (int g = 0; g < 3; ++g) {
                        int row = g * 16 + (lane & 15);
                        int off = row * 128 + (kb ^ ((row & 7) << 4));
                        Bh[g] = __builtin_bit_cast(bf16x8, *(const ushort8*)(&BsB[cur][0][0] + off));
                        Bl[g] = __builtin_bit_cast(bf16x8, *(const ushort8*)(&BsB[cur][1][0] + off));
                    }
                    #pragma unroll
                    for (int rt = 0; rt < 2; ++rt)
                        #pragma unroll
                        for (int g = 0; g < 3; ++g) {
                            f32x4 c = acc[rt][g];
                            c = __builtin_amdgcn_mfma_f32_16x16x32_bf16(Ah[rt], Bh[g], c, 0, 0, 0);
                            c = __builtin_amdgcn_mfma_f32_16x16x32_bf16(Al[rt], Bh[g], c, 0, 0, 0);
                            c = __builtin_amdgcn_mfma_f32_16x16x32_bf16(Ah[rt], Bl[g], c, 0, 0, 0);
                            acc[rt][g] = c;
                        }
                }
            };

            f32x4 accX[2][3], accH[2][3];
            const f32x4 zv = {0.f, 0.f, 0.f, 0.f};
            #pragma unroll
            for (int rt = 0; rt < 2; ++rt)
                #pragma unroll
                for (int g = 0; g < 3; ++g) { accX[rt][g] = zv; accH[rt][g] = zv; }

            if (XS) {
                // 3-deep pipeline, counted vmcnt (11 loads/wave/stage), raw barriers
                stageDMA(0, 0);
                stageDMA(1, 1);
                for (int ch = 0; ch < 32; ++ch) {
                    const int cur = ch % 3;
                    if (ch < 30) stageDMA(ch + 2, (ch + 2) % 3);
                    if (ch < 30)       asm volatile("s_waitcnt vmcnt(22) lgkmcnt(0)" ::: "memory");
                    else if (ch == 30) asm volatile("s_waitcnt vmcnt(11) lgkmcnt(0)" ::: "memory");
                    else               asm volatile("s_waitcnt vmcnt(0) lgkmcnt(0)"  ::: "memory");
                    __builtin_amdgcn_s_barrier();            // B1: all waves' cur-loads landed
                    asm volatile("" ::: "memory");
                    if (ch < 16) compute(cur, accX); else compute(cur, accH);
                    asm volatile("" ::: "memory");
                    __builtin_amdgcn_s_barrier();            // B2: all waves done reading cur
                    asm volatile("" ::: "memory");
                }
            } else {
                stageF(0, 0);
                __syncthreads();
                for (int ch = 0; ch < 32; ++ch) {
                    const int cur = ch & 1;
                    if (ch + 1 < 32) stageF(ch + 1, cur ^ 1);
                    if (ch < 16) compute(cur, accX); else compute(cur, accH);
                    __syncthreads();
                }
            }

            // ---- gates + state update; h written as coherent atomic bf16 pairs ----
            #pragma unroll
            for (int rt = 0; rt < 2; ++rt)
                #pragma unroll
                for (int q = 0; q < 4; ++q) {
                    const int b = wave * 32 + rt * 16 + (lane >> 4) * 4 + q;
                    float xr = accX[rt][0][q], hr = accH[rt][0][q];
                    float xz = accX[rt][1][q], hz = accH[rt][1][q];
                    float xn = accX[rt][2][q], hn_ = accH[rt][2][q];
                    float r  = 1.0f / (1.0f + expf(-(xr + b_ir + hr + b_hr)));
                    float z  = 1.0f / (1.0f + expf(-(xz + b_iz + hz + b_hz)));
                    float n  = tanhf(xn + b_in + r * (hn_ + b_hn));
                    float h  = (1.0f - z) * n + z * hreg[rt * 4 + q];
                    hreg[rt * 4 + q] = h;
                    unsigned short hi, lo; split_bf16(h, hi, lo);
                    __hip_atomic_store((unsigned short*)(Hd + hoff(b, 0)), hi,
                                       __ATOMIC_RELAXED, __HIP_MEMORY_SCOPE_AGENT);
                    __hip_atomic_store((unsigned short*)(Hd + hoff(b, 1)), lo,
                                       __ATOMIC_RELAXED, __HIP_MEMORY_SCOPE_AGENT);
                }
        }
        grid_barrier(cnt, target);
    }
}

__global__ void pred_kernel(const char* __restrict__ hs,
                            const float* __restrict__ linW,
                            const float* __restrict__ linb,
                            float* __restrict__ out) {
    const int b = blockIdx.x, l = threadIdx.x;   // 64 threads
    const char* slot = hs + 7 * SLOT_B;
    float s = 0.f;
    for (int u = l; u < Hh; u += 64) {
        int kc = u >> 6, col = u & 63;
        size_t o = (size_t)kc * 16384 + (size_t)(b * 128 + (((col * 2) ^ ((b & 7) << 4))));
        float hv = b2f(*(const unsigned short*)(slot + o))
                 + b2f(*(const unsigned short*)(slot + 262144 + o));
        s += hv * linW[u];
    }
    #pragma unroll
    for (int off = 32; off > 0; off >>= 1) s += __shfl_down(s, off);
    if (l == 0) out[b] = s + linb[0];
}

extern "C" void kernel_launch(void* const* d_in, const int* in_sizes, int n_in,
                              void* d_out, int out_size, void* d_ws, size_t ws_size,
                              hipStream_t stream) {
    const float* rand_in = (const float*)d_in[1];
    const float* h0      = (const float*)d_in[2];
    const float* Wih0    = (const float*)d_in[7];
    const float* Whh0    = (const float*)d_in[8];
    const float* bih0    = (const float*)d_in[9];
    const float* bhh0    = (const float*)d_in[10];
    const float* Wih1    = (const float*)d_in[11];
    const float* Whh1    = (const float*)d_in[12];
    const float* bih1    = (const float*)d_in[13];
    const float* bhh1    = (const float*)d_in[14];
    const float* linW    = (const float*)d_in[15];
    const float* linb    = (const float*)d_in[16];
    float* out = (float*)d_out;

    char*     ws  = (char*)d_ws;
    unsigned* cnt = (unsigned*)d_ws;
    char*     hsl = ws + OFF_H;

    const bool xsl = (ws_size >= WS_FULL);

    wsplit_kernel<<<6144, 256, 0, stream>>>(Wih0, Whh0, Wih1, Whh1,
                                            (unsigned short*)(ws + OFF_W));
    hinit_kernel<<<256, 256, 0, stream>>>(h0, hsl, cnt);
    if (xsl) {
        xsplit_kernel<<<24576, 256, 0, stream>>>(rand_in, ws + OFF_X);
        gru_persistent<true><<<NWG, BLK, 0, stream>>>(rand_in, bih0, bhh0, bih1, bhh1, cnt, ws);
    } else {
        gru_persistent<false><<<NWG, BLK, 0, stream>>>(rand_in, bih0, bhh0, bih1, bhh1, cnt, ws);
    }
    pred_kernel<<<Bb, 64, 0, stream>>>(hsl, linW, linb, out);
}